// Round 2
// baseline (339.078 us; speedup 1.0000x reference)
//
#include <hip/hip_runtime.h>

// SubsetOperator (relaxed top-K=16) in exp-space, TWO-PASS:
//   The iteration  { Z = sum(e); oh = e/Z; kh += oh; e *= (1-oh) }  only needs
//   the scalars Z_it to advance. So:
//   Pass 1: evolve e only (32 live regs) through the 16 barrier-reductions,
//           capturing inv_it = rcp(Z_it) into SGPRs (readfirstlane).
//   Pass 2: re-read inputs (L2-hot, block-local 64 KB), recompute e
//           bit-identically, replay 16 iters element-outer with scalar inv —
//           barrier-free, shuffle-free, pure independent-chain VALU.
// Why: v2 (147 us dispatch) was latency-bound: VALUBusy 46%, occupancy 35%,
//   64 live floats vs 60 reported VGPRs (spill), 16 block barriers on the
//   critical path. Halving live state per phase fits 64 VGPR ->
//   __launch_bounds__(512,8) -> 4 blocks/CU so barriers overlap across blocks.

constexpr int N_COLS  = 8192;
constexpr int THREADS = 512;
constexpr int PER     = N_COLS / THREADS;   // 16 elements per thread per row
constexpr int ROWS_PB = 2;                  // rows per block
constexpr int NWAVES  = THREADS / 64;       // 8 waves
constexpr int KITER   = 16;

template<int PAT>
__device__ __forceinline__ float swz_add(float v) {
    // ds_swizzle BitMode: offset = (xor_mask<<10) | 0x1F (and-mask keeps lane)
    int s = __builtin_amdgcn_ds_swizzle(__float_as_int(v), PAT);
    return v + __int_as_float(s);
}

__device__ __forceinline__ float rfl(float v) {
    return __int_as_float(__builtin_amdgcn_readfirstlane(__float_as_int(v)));
}

__device__ __forceinline__ float tree16(const float* v) {
    return (((v[0] + v[1]) + (v[2] + v[3])) + ((v[4] + v[5]) + (v[6] + v[7])))
         + (((v[8] + v[9]) + (v[10] + v[11])) + ((v[12] + v[13]) + (v[14] + v[15])));
}

__global__ __launch_bounds__(THREADS, 8)
void subset_op_kernel(const float* __restrict__ scores,
                      const float* __restrict__ gnoise,
                      float* __restrict__ out)
{
    const int t    = threadIdx.x;
    const int wave = t >> 6;
    const int lane = t & 63;
    const size_t base = (size_t)blockIdx.x * (size_t)(ROWS_PB * N_COLS);
    constexpr int ROW4 = N_COLS / 4;          // float4s per row

    const float4* s4 = (const float4*)(scores + base);
    const float4* g4 = (const float4*)(gnoise + base);
    float4*       o4 = (float4*)(out + base);

    // ---------------- PASS 1: compute inv_it = rcp(Z_it), e-only ----------------
    float e0[PER], e1[PER];

    #pragma unroll
    for (int c = 0; c < PER / 4; ++c) {
        float4 a  = s4[c * THREADS + t];
        float4 b  = g4[c * THREADS + t];
        e0[c*4 + 0] = __expf(a.x + b.x);
        e0[c*4 + 1] = __expf(a.y + b.y);
        e0[c*4 + 2] = __expf(a.z + b.z);
        e0[c*4 + 3] = __expf(a.w + b.w);
        float4 a2 = s4[ROW4 + c * THREADS + t];
        float4 b2 = g4[ROW4 + c * THREADS + t];
        e1[c*4 + 0] = __expf(a2.x + b2.x);
        e1[c*4 + 1] = __expf(a2.y + b2.y);
        e1[c*4 + 2] = __expf(a2.z + b2.z);
        e1[c*4 + 3] = __expf(a2.w + b2.w);
    }
    // (no max-shift: exp(s0) <= ~1e10 for this distribution, fp32-safe;
    //  softmax is shift-invariant)

    float z0 = tree16(e0);
    float z1 = tree16(e1);

    // red[buf][wave] = float2(row0_wavesum, row1_wavesum); double-buffered,
    // one barrier per iteration (write(it,buf) -> barrier -> read(buf); next
    // write to buf is at it+2, after barrier it+1, after all it-reads).
    __shared__ float2 red[2][NWAVES];

    float iv0[KITER], iv1[KITER];             // wave-uniform -> SGPRs via rfl

    #pragma unroll
    for (int it = 0; it < KITER; ++it) {
        // 5-level ds_swizzle xor butterfly within 32-lane halves, then one
        // cross-half exchange -> full 64-lane wave sum in every lane.
        float r0 = z0, r1 = z1;
        r0 = swz_add<0x041F>(r0);  r1 = swz_add<0x041F>(r1);   // xor 1
        r0 = swz_add<0x081F>(r0);  r1 = swz_add<0x081F>(r1);   // xor 2
        r0 = swz_add<0x101F>(r0);  r1 = swz_add<0x101F>(r1);   // xor 4
        r0 = swz_add<0x201F>(r0);  r1 = swz_add<0x201F>(r1);   // xor 8
        r0 = swz_add<0x401F>(r0);  r1 = swz_add<0x401F>(r1);   // xor 16
        r0 += __shfl_xor(r0, 32, 64);
        r1 += __shfl_xor(r1, 32, 64);
        if (lane == 0) red[it & 1][wave] = make_float2(r0, r1);
        __syncthreads();

        float Z0, Z1;
        {
            // 8 float2 wave-partials = 4 float4 broadcast reads
            const float4* rp = (const float4*)(&red[it & 1][0]);
            float4 v0 = rp[0], v1 = rp[1], v2 = rp[2], v3 = rp[3];
            Z0 = ((v0.x + v0.z) + (v1.x + v1.z)) + ((v2.x + v2.z) + (v3.x + v3.z));
            Z1 = ((v0.y + v0.w) + (v1.y + v1.w)) + ((v2.y + v2.w) + (v3.y + v3.w));
        }
        const float i0 = rfl(__builtin_amdgcn_rcpf(Z0));   // v_rcp_f32, ~1 ulp
        const float i1 = rfl(__builtin_amdgcn_rcpf(Z1));
        iv0[it] = i0;
        iv1[it] = i1;

        if (it < KITER - 1) {
            // evolve e, fused next-partial (4-way accumulator trees)
            float za[4] = {0.f, 0.f, 0.f, 0.f};
            float zb[4] = {0.f, 0.f, 0.f, 0.f};
            #pragma unroll
            for (int j = 0; j < PER; ++j) {
                float oh0 = e0[j] * i0;
                e0[j] = __builtin_fmaf(-oh0, e0[j], e0[j]);   // e *= (1 - oh)
                za[j & 3] += e0[j];
                float oh1 = e1[j] * i1;
                e1[j] = __builtin_fmaf(-oh1, e1[j], e1[j]);
                zb[j & 3] += e1[j];
            }
            z0 = (za[0] + za[1]) + (za[2] + za[3]);
            z1 = (zb[0] + zb[1]) + (zb[2] + zb[3]);
        }
    }

    // ---------------- PASS 2: replay with scalar inv, accumulate kh ------------
    // Inputs re-read are block-local 64 KB touched ~10 us ago -> L2/L3 hot.
    // exp recomputed with identical ops -> bit-identical e -> consistent with
    // the Z_it captured above. No barriers, no shuffles: pure VALU streaming.
    #pragma unroll
    for (int c = 0; c < PER / 4; ++c) {
        float4 a  = s4[c * THREADS + t];
        float4 b  = g4[c * THREADS + t];
        float4 a2 = s4[ROW4 + c * THREADS + t];
        float4 b2 = g4[ROW4 + c * THREADS + t];
        float p[8], kh[8];
        p[0] = __expf(a.x + b.x);   p[1] = __expf(a.y + b.y);
        p[2] = __expf(a.z + b.z);   p[3] = __expf(a.w + b.w);
        p[4] = __expf(a2.x + b2.x); p[5] = __expf(a2.y + b2.y);
        p[6] = __expf(a2.z + b2.z); p[7] = __expf(a2.w + b2.w);
        #pragma unroll
        for (int q = 0; q < 8; ++q) kh[q] = 0.0f;

        #pragma unroll
        for (int it = 0; it < KITER; ++it) {
            const float u0 = iv0[it];
            const float u1 = iv1[it];
            #pragma unroll
            for (int q = 0; q < 4; ++q) {
                float oh0 = p[q] * u0;                        // onehot (TAU=1)
                kh[q] += oh0;
                p[q] = __builtin_fmaf(-oh0, p[q], p[q]);
                float oh1 = p[4 + q] * u1;
                kh[4 + q] += oh1;
                p[4 + q] = __builtin_fmaf(-oh1, p[4 + q], p[4 + q]);
            }
        }

        float4 v, w;
        v.x = kh[0]; v.y = kh[1]; v.z = kh[2]; v.w = kh[3];
        w.x = kh[4]; w.y = kh[5]; w.z = kh[6]; w.w = kh[7];
        o4[c * THREADS + t]        = v;
        o4[ROW4 + c * THREADS + t] = w;
    }
}

extern "C" void kernel_launch(void* const* d_in, const int* in_sizes, int n_in,
                              void* d_out, int out_size, void* d_ws, size_t ws_size,
                              hipStream_t stream)
{
    const float* scores = (const float*)d_in[0];
    const float* gnoise = (const float*)d_in[1];
    float* out = (float*)d_out;
    const int rows = in_sizes[0] / N_COLS;     // 4096

    subset_op_kernel<<<rows / ROWS_PB, THREADS, 0, stream>>>(scores, gnoise, out);
}